// Round 9
// baseline (376.118 us; speedup 1.0000x reference)
//
#include <hip/hip_runtime.h>
#include <hip/hip_bf16.h>

#define NN  16
#define WT  256
#define TT  2048
#define DIM 256
#define TBT 8      // t-values per block in fallback fused kernel
#define TBS 16     // t-values per block in fused score+out kernel

typedef __attribute__((ext_vector_type(8))) short short8_t;  // 8 bf16 (4 VGPRs)
typedef __attribute__((ext_vector_type(4))) float f32x4;     // MFMA acc

__device__ __forceinline__ float fast_rcp(float x){ return __builtin_amdgcn_rcpf(x); }

__device__ __forceinline__ float silu_f(float x){
    return x * fast_rcp(1.0f + __expf(-x));
}

__device__ __forceinline__ unsigned short f2bf(float x){
    union { float f; unsigned u; } v; v.f = x;
    unsigned r = v.u + 0x7FFFu + ((v.u >> 16) & 1u);   // round-to-nearest-even
    return (unsigned short)(r >> 16);
}

__device__ __forceinline__ void fma4(float4& a, float s, const float4& f){
    a.x = fmaf(s, f.x, a.x); a.y = fmaf(s, f.y, a.y);
    a.z = fmaf(s, f.z, a.z); a.w = fmaf(s, f.w, a.w);
}

// ---------------- Kernel A: per-n inclusive cumsum of durations ----------------
__global__ __launch_bounds__(WT) void cumsum_k(const float* __restrict__ dur,
                                               float* __restrict__ ts,
                                               float* __restrict__ te){
    int n = blockIdx.x, w = threadIdx.x;
    __shared__ float s[WT];
    float d = dur[n*WT + w];
    s[w] = d;
    __syncthreads();
    for (int off = 1; off < WT; off <<= 1){
        float v = (w >= off) ? s[w-off] : 0.0f;
        __syncthreads();
        s[w] += v;
        __syncthreads();
    }
    float e = s[w];
    te[n*WT + w] = e;
    ts[n*WT + w] = e - d;
}

// ------- Kernel B: conv(3,256->8)+BN+SiLU both branches, fold into v1/v2 -------
__global__ __launch_bounds__(256) void prep_k(
    const float* __restrict__ feat,
    const float* __restrict__ c1w, const float* __restrict__ c1b,
    const float* __restrict__ g1,  const float* __restrict__ be1,
    const float* __restrict__ m1,  const float* __restrict__ vv1,
    const float* __restrict__ c2w, const float* __restrict__ c2b,
    const float* __restrict__ g2,  const float* __restrict__ be2,
    const float* __restrict__ m2,  const float* __restrict__ vv2,
    const float* __restrict__ sb1w1, const float* __restrict__ sb1b1,
    const float* __restrict__ sb2w1, const float* __restrict__ sb2b1,
    const float* __restrict__ ts, const float* __restrict__ te,
    float* __restrict__ v1o, float* __restrict__ v2o)
{
    int w = blockIdx.x, n = blockIdx.y;
    int tid = threadIdx.x;              // channel c
    const float* fb = feat + (size_t)(n*WT)*DIM;
    float fm = (w > 0)    ? fb[(size_t)(w-1)*DIM + tid] : 0.0f;
    float f0 =              fb[(size_t) w   *DIM + tid];
    float fp = (w < WT-1) ? fb[(size_t)(w+1)*DIM + tid] : 0.0f;

    float pl[8], pr[8];
    #pragma unroll
    for (int o = 0; o < 8; o++){
        const float* wp = c1w + (size_t)(o*DIM + tid)*3;
        pl[o] = fmaf(fm, wp[0], fmaf(f0, wp[1], fp*wp[2]));
        const float* wq = c2w + (size_t)(o*DIM + tid)*3;
        pr[o] = fmaf(fm, wq[0], fmaf(f0, wq[1], fp*wq[2]));
    }
    #pragma unroll
    for (int o = 0; o < 8; o++){
        #pragma unroll
        for (int off = 32; off; off >>= 1){
            pl[o] += __shfl_xor(pl[o], off);
            pr[o] += __shfl_xor(pr[o], off);
        }
    }
    __shared__ float sws[4][16];
    int wave = tid >> 6, lane = tid & 63;
    if (lane == 0){
        #pragma unroll
        for (int o = 0; o < 8; o++){ sws[wave][o] = pl[o]; sws[wave][8+o] = pr[o]; }
    }
    __syncthreads();
    __shared__ float slr[16];   // [0..7]=left(SiLU'd), [8..15]=right
    if (tid < 16){
        float s = sws[0][tid] + sws[1][tid] + sws[2][tid] + sws[3][tid];
        int o = tid & 7; bool isr = tid >= 8;
        float bias = isr ? c2b[o] : c1b[o];
        float mm   = isr ? m2[o]  : m1[o];
        float vv   = isr ? vv2[o] : vv1[o];
        float gg   = isr ? g2[o]  : g1[o];
        float bb   = isr ? be2[o] : be1[o];
        float y = s + bias;
        y = (y - mm) * rsqrtf(vv + 1e-5f);
        y = y * gg + bb;
        slr[tid] = silu_f(y);
    }
    __syncthreads();
    float start = ts[n*WT + w], end = te[n*WT + w];
    if (tid < 16){
        int j = tid;
        float acc = sb2b1[j] - start*sb2w1[j] + end*sb2w1[16 + j];
        #pragma unroll
        for (int o = 0; o < 8; o++) acc = fmaf(slr[8+o], sb2w1[(2+o)*16 + j], acc);
        v2o[(size_t)(n*WT + w)*16 + j] = acc;
    } else if (tid < 18){
        int p = tid - 16;
        float acc = sb1b1[p] - start*sb1w1[p] + end*sb1w1[2 + p];
        #pragma unroll
        for (int o = 0; o < 8; o++) acc = fmaf(slr[o], sb1w1[(2+o)*2 + p], acc);
        v1o[(size_t)(n*WT + w)*2 + p] = acc;
    }
}

// ------- Kernel B2: pack feat into B-fragment bf16 layout [n][w/32][d][w%32] -------
__global__ __launch_bounds__(256) void featpack_k(const float* __restrict__ feat,
                                                  unsigned short* __restrict__ featP)
{
    int kb = blockIdx.x, n = blockIdx.y;   // kb = 0..7 (k-block of 32 w's)
    int d = threadIdx.x;
    const float* fb = feat + (size_t)n*WT*DIM + (size_t)kb*32*DIM + d;
    unsigned short* op = featP + ((size_t)(n*8 + kb)*DIM + d)*32;
    unsigned short buf[32];
    #pragma unroll
    for (int e = 0; e < 32; e++) buf[e] = f2bf(fb[(size_t)e*DIM]);   // coalesced reads
    #pragma unroll
    for (int g = 0; g < 4; g++){
        uint4 u;
        u.x = (unsigned)buf[g*8+0] | ((unsigned)buf[g*8+1] << 16);
        u.y = (unsigned)buf[g*8+2] | ((unsigned)buf[g*8+3] << 16);
        u.z = (unsigned)buf[g*8+4] | ((unsigned)buf[g*8+5] << 16);
        u.w = (unsigned)buf[g*8+6] | ((unsigned)buf[g*8+7] << 16);
        *(uint4*)(op + g*8) = u;
    }
}

// ------- Kernel C: fused scores -> softmax -> MFMA GEMM -> out ----------------
// Block = 256 threads, 16 t-values.  Phase 1 (R5's known-good scalar matvec,
// LDS-staged weights): thread w computes 16 scores + C, batched softmax,
// writes bf16 wsm[t][w] to LDS (+8 pad).  Phase 2: 4 waves run the
// 16t x 256d GEMM, A-frags from LDS, B-frags from featP, wc epilogue fused.
__global__ __launch_bounds__(256) void scoreout_k(
    const float* __restrict__ Tg,
    const float* __restrict__ v1g, const float* __restrict__ v2g,
    const float* __restrict__ sb1w1, const float* __restrict__ sb1w2, const float* __restrict__ sb1b2,
    const float* __restrict__ sb2w1, const float* __restrict__ sb2w2, const float* __restrict__ sb2b2,
    const float* __restrict__ p2w, const float* __restrict__ p2b,
    const unsigned short* __restrict__ featP,
    const float* __restrict__ p1w, const float* __restrict__ p1b,
    float* __restrict__ out)
{
    int n   = blockIdx.y;
    int t0  = blockIdx.x * TBS;
    int tid = threadIdx.x;
    int w   = tid;
    int lane = tid & 63, wave = tid >> 6;

    __shared__ float s_w2[16*16];
    __shared__ float s_u2[16], s_b2[16], s_p2w[16];
    __shared__ float s_u1[2], s_w21[4], s_b21[2];
    __shared__ float s_xa[4][TBS];
    __shared__ float s_xs[4][TBS];
    __shared__ float s_xc0[4][TBS], s_xc1[4][TBS];
    __shared__ unsigned short s_wsmT[TBS][WT + 8];   // [t][w], +8 pad breaks b128 bank conflicts
    __shared__ float s_wc0[TBS], s_wc1[TBS];

    s_w2[tid] = sb2w2[tid];
    if (tid < 16){
        s_u2[tid]  = sb2w1[tid] - sb2w1[16 + tid];
        s_b2[tid]  = sb2b2[tid];
        s_p2w[tid] = p2w[tid];
    } else if (tid < 18){
        int p = tid - 16;
        s_u1[p]  = sb1w1[p] - sb1w1[2 + p];
        s_b21[p] = sb1b2[p];
    } else if (tid < 22){
        s_w21[tid - 18] = sb1w2[tid - 18];
    }
    __syncthreads();

    float v2r[16];
    {
        const float4* vp = (const float4*)(v2g + (size_t)(n*WT + w)*16);
        float4 a = vp[0], b = vp[1], c = vp[2], d = vp[3];
        v2r[0]=a.x; v2r[1]=a.y; v2r[2]=a.z; v2r[3]=a.w;
        v2r[4]=b.x; v2r[5]=b.y; v2r[6]=b.z; v2r[7]=b.w;
        v2r[8]=c.x; v2r[9]=c.y; v2r[10]=c.z; v2r[11]=c.w;
        v2r[12]=d.x; v2r[13]=d.y; v2r[14]=d.z; v2r[15]=d.w;
    }
    float v1r0, v1r1;
    {
        const float* vp = v1g + (size_t)(n*WT + w)*2;
        v1r0 = vp[0]; v1r1 = vp[1];
    }
    float p2bv = p2b[0];
    float tv[TBS];
    #pragma unroll
    for (int ti = 0; ti < TBS; ti++) tv[ti] = Tg[t0 + ti];   // uniform -> s_load

    // ---- scores: R5 scalar matvec, ti in pairs ----
    float scores[TBS];
    #pragma unroll
    for (int tp = 0; tp < TBS; tp += 2){
        float h2a[16], h2b[16];
        #pragma unroll
        for (int j = 0; j < 16; j++){ float b = s_b2[j]; h2a[j] = b; h2b[j] = b; }
        #pragma unroll
        for (int i = 0; i < 16; i++){
            float u = s_u2[i], v = v2r[i];
            float aa = silu_f(fmaf(tv[tp],   u, v));
            float ab = silu_f(fmaf(tv[tp+1], u, v));
            #pragma unroll
            for (int j = 0; j < 16; j++){
                float wv = s_w2[i*16 + j];
                h2a[j] = fmaf(aa, wv, h2a[j]);
                h2b[j] = fmaf(ab, wv, h2b[j]);
            }
        }
        float sa = p2bv, sb = p2bv;
        #pragma unroll
        for (int j = 0; j < 16; j++){
            float pw = s_p2w[j];
            sa = fmaf(silu_f(h2a[j]), pw, sa);
            sb = fmaf(silu_f(h2b[j]), pw, sb);
        }
        scores[tp] = sa; scores[tp+1] = sb;
    }

    // ---- C values ----
    float c0r[TBS], c1r[TBS];
    {
        float u10 = s_u1[0], u11 = s_u1[1];
        float w00 = s_w21[0], w01 = s_w21[1], w10 = s_w21[2], w11 = s_w21[3];
        float b0 = s_b21[0], b1 = s_b21[1];
        #pragma unroll
        for (int ti = 0; ti < TBS; ti++){
            float gl0 = silu_f(fmaf(tv[ti], u10, v1r0));
            float gl1 = silu_f(fmaf(tv[ti], u11, v1r1));
            c0r[ti] = silu_f(fmaf(gl0, w00, fmaf(gl1, w10, b0)));
            c1r[ti] = silu_f(fmaf(gl0, w01, fmaf(gl1, w11, b1)));
        }
    }

    // ---- batched softmax over w for all 16 t (2 barriers) ----
    float m[TBS];
    #pragma unroll
    for (int ti = 0; ti < TBS; ti++) m[ti] = scores[ti];
    #pragma unroll
    for (int off = 32; off; off >>= 1){
        #pragma unroll
        for (int ti = 0; ti < TBS; ti++) m[ti] = fmaxf(m[ti], __shfl_xor(m[ti], off));
    }
    if (lane == 0){
        #pragma unroll
        for (int ti = 0; ti < TBS; ti++) s_xa[wave][ti] = m[ti];
    }
    __syncthreads();
    #pragma unroll
    for (int ti = 0; ti < TBS; ti++)
        m[ti] = fmaxf(fmaxf(s_xa[0][ti], s_xa[1][ti]), fmaxf(s_xa[2][ti], s_xa[3][ti]));

    // e overwrites scores; pc0/pc1 overwrite c0r/c1r; ps reuses m
    #pragma unroll
    for (int ti = 0; ti < TBS; ti++){
        float e = __expf(scores[ti] - m[ti]);
        scores[ti] = e;
        m[ti]   = e;             // ps
        c0r[ti] = e * c0r[ti];   // pc0
        c1r[ti] = e * c1r[ti];   // pc1
    }
    #pragma unroll
    for (int off = 32; off; off >>= 1){
        #pragma unroll
        for (int ti = 0; ti < TBS; ti++){
            m[ti]   += __shfl_xor(m[ti],   off);
            c0r[ti] += __shfl_xor(c0r[ti], off);
            c1r[ti] += __shfl_xor(c1r[ti], off);
        }
    }
    if (lane == 0){
        #pragma unroll
        for (int ti = 0; ti < TBS; ti++){
            s_xs[wave][ti]  = m[ti];
            s_xc0[wave][ti] = c0r[ti];
            s_xc1[wave][ti] = c1r[ti];
        }
    }
    __syncthreads();

    #pragma unroll
    for (int ti = 0; ti < TBS; ti++){
        float S  = s_xs[0][ti] + s_xs[1][ti] + s_xs[2][ti] + s_xs[3][ti];
        float rS = fast_rcp(S);
        s_wsmT[ti][w] = f2bf(scores[ti] * rS);
    }
    if (tid < TBS){
        int ti = tid;
        float S  = s_xs[0][ti] + s_xs[1][ti] + s_xs[2][ti] + s_xs[3][ti];
        float rS = fast_rcp(S);
        s_wc0[ti] = (s_xc0[0][ti] + s_xc0[1][ti] + s_xc0[2][ti] + s_xc0[3][ti]) * rS;
        s_wc1[ti] = (s_xc1[0][ti] + s_xc1[1][ti] + s_xc1[2][ti] + s_xc1[3][ti]) * rS;
    }
    __syncthreads();

    // ---- Phase 2: 16t x 256d GEMM; wave handles 16t x 64d (dbase = wave*4) ----
    int l15 = lane & 15, quad = lane >> 4;
    int dbase = wave * 4;

    f32x4 acc[4];
    #pragma unroll
    for (int dt = 0; dt < 4; dt++) acc[dt] = (f32x4){0.f, 0.f, 0.f, 0.f};

    const unsigned short* aRow = &s_wsmT[l15][0];    // A row m = t = lane&15
    #pragma unroll
    for (int kb = 0; kb < 8; kb++){
        short8_t af = *(const short8_t*)(aRow + kb*32 + quad*8);
        const unsigned short* bp = featP + ((size_t)(n*8 + kb)*DIM + dbase*16 + l15)*32 + quad*8;
        #pragma unroll
        for (int dt = 0; dt < 4; dt++){
            short8_t bf = *(const short8_t*)(bp + (size_t)dt*16*32);
            acc[dt] = __builtin_amdgcn_mfma_f32_16x16x32_bf16(af, bf, acc[dt], 0, 0, 0);
        }
    }

    // epilogue: + wc0*p1w[0,d] + wc1*p1w[1,d] + p1b[d]
    float wc0[4], wc1[4];
    #pragma unroll
    for (int r = 0; r < 4; r++){
        wc0[r] = s_wc0[quad*4 + r];
        wc1[r] = s_wc1[quad*4 + r];
    }
    float* obase = out + ((size_t)(n*TT + t0 + quad*4))*DIM;
    #pragma unroll
    for (int dt = 0; dt < 4; dt++){
        int d = (dbase + dt)*16 + l15;   // D col
        float pa = p1w[d], pb2 = p1w[DIM + d], pc = p1b[d];
        #pragma unroll
        for (int r = 0; r < 4; r++){     // D row = quad*4 + r  (t = t0 + quad*4 + r)
            float val = acc[dt][r] + fmaf(wc0[r], pa, fmaf(wc1[r], pb2, pc));
            obase[(size_t)r*DIM + d] = val;
        }
    }
}

// ---------------- Fallback fused kernel (R1, known-good) if ws too small ----------------
__global__ __launch_bounds__(256) void fused_k(
    const float* __restrict__ Tg, const float* __restrict__ feat,
    const float* __restrict__ v1g, const float* __restrict__ v2g,
    const float* __restrict__ sb1w1, const float* __restrict__ sb1w2, const float* __restrict__ sb1b2,
    const float* __restrict__ sb2w1, const float* __restrict__ sb2w2, const float* __restrict__ sb2b2,
    const float* __restrict__ p1w, const float* __restrict__ p1b,
    const float* __restrict__ p2w, const float* __restrict__ p2b,
    float* __restrict__ out)
{
    int n   = blockIdx.y;
    int t0  = blockIdx.x * TBT;
    int tid = threadIdx.x;
    int w   = tid;
    int lane = tid & 63, wave = tid >> 6;

    __shared__ float s_w2[16*16];
    __shared__ float s_u2[16], s_b2[16], s_p2w[16];
    __shared__ float s_u1[2], s_w21[4], s_b21[2];
    __shared__ float s_wsmT[WT][TBT];
    __shared__ float s_xa[4][TBT];
    __shared__ float s_xs[4][TBT];
    __shared__ float s_xc0[4][TBT], s_xc1[4][TBT];
    __shared__ float s_wc0[TBT], s_wc1[TBT];
    __shared__ float s_out[4][DIM];

    s_w2[tid] = sb2w2[tid];
    if (tid < 16){
        s_u2[tid]  = sb2w1[tid] - sb2w1[16 + tid];
        s_b2[tid]  = sb2b2[tid];
        s_p2w[tid] = p2w[tid];
    } else if (tid < 18){
        int p = tid - 16;
        s_u1[p]  = sb1w1[p] - sb1w1[2 + p];
        s_b21[p] = sb1b2[p];
    } else if (tid < 22){
        s_w21[tid - 18] = sb1w2[tid - 18];
    }
    __syncthreads();

    float v2r[16];
    {
        const float4* vp = (const float4*)(v2g + (size_t)(n*WT + w)*16);
        float4 a = vp[0], b = vp[1], c = vp[2], d = vp[3];
        v2r[0]=a.x; v2r[1]=a.y; v2r[2]=a.z; v2r[3]=a.w;
        v2r[4]=b.x; v2r[5]=b.y; v2r[6]=b.z; v2r[7]=b.w;
        v2r[8]=c.x; v2r[9]=c.y; v2r[10]=c.z; v2r[11]=c.w;
        v2r[12]=d.x; v2r[13]=d.y; v2r[14]=d.z; v2r[15]=d.w;
    }
    float v1r0, v1r1;
    {
        const float* vp = v1g + (size_t)(n*WT + w)*2;
        v1r0 = vp[0]; v1r1 = vp[1];
    }
    float p2bv = p2b[0];
    float tv[TBT];
    #pragma unroll
    for (int ti = 0; ti < TBT; ti++) tv[ti] = Tg[t0 + ti];

    float scores[TBT];
    #pragma unroll
    for (int tp = 0; tp < TBT; tp += 2){
        float h2a[16], h2b[16];
        #pragma unroll
        for (int j = 0; j < 16; j++){ float b = s_b2[j]; h2a[j] = b; h2b[j] = b; }
        #pragma unroll
        for (int i = 0; i < 16; i++){
            float u = s_u2[i], v = v2r[i];
            float aa = silu_f(fmaf(tv[tp],   u, v));
            float ab = silu_f(fmaf(tv[tp+1], u, v));
            #pragma unroll
            for (int j = 0; j < 16; j++){
                float wv = s_w2[i*16 + j];
                h2a[j] = fmaf(aa, wv, h2a[j]);
                h2b[j] = fmaf(ab, wv, h2b[j]);
            }
        }
        float sa = p2bv, sb = p2bv;
        #pragma unroll
        for (int j = 0; j < 16; j++){
            float pw = s_p2w[j];
            sa = fmaf(silu_f(h2a[j]), pw, sa);
            sb = fmaf(silu_f(h2b[j]), pw, sb);
        }
        scores[tp] = sa; scores[tp+1] = sb;
    }

    float c0r[TBT], c1r[TBT];
    {
        float u10 = s_u1[0], u11 = s_u1[1];
        float w00 = s_w21[0], w01 = s_w21[1], w10 = s_w21[2], w11 = s_w21[3];
        float b0 = s_b21[0], b1 = s_b21[1];
        #pragma unroll
        for (int ti = 0; ti < TBT; ti++){
            float gl0 = silu_f(fmaf(tv[ti], u10, v1r0));
            float gl1 = silu_f(fmaf(tv[ti], u11, v1r1));
            c0r[ti] = silu_f(fmaf(gl0, w00, fmaf(gl1, w10, b0)));
            c1r[ti] = silu_f(fmaf(gl0, w01, fmaf(gl1, w11, b1)));
        }
    }

    float m[TBT];
    #pragma unroll
    for (int ti = 0; ti < TBT; ti++) m[ti] = scores[ti];
    #pragma unroll
    for (int off = 32; off; off >>= 1){
        #pragma unroll
        for (int ti = 0; ti < TBT; ti++) m[ti] = fmaxf(m[ti], __shfl_xor(m[ti], off));
    }
    if (lane == 0){
        #pragma unroll
        for (int ti = 0; ti < TBT; ti++) s_xa[wave][ti] = m[ti];
    }
    __syncthreads();
    #pragma unroll
    for (int ti = 0; ti < TBT; ti++)
        m[ti] = fmaxf(fmaxf(s_xa[0][ti], s_xa[1][ti]), fmaxf(s_xa[2][ti], s_xa[3][ti]));

    float e[TBT], ps[TBT], pc0[TBT], pc1[TBT];
    #pragma unroll
    for (int ti = 0; ti < TBT; ti++){
        e[ti]  = __expf(scores[ti] - m[ti]);
        ps[ti] = e[ti];
        pc0[ti] = e[ti] * c0r[ti];
        pc1[ti] = e[ti] * c1r[ti];
    }
    #pragma unroll
    for (int off = 32; off; off >>= 1){
        #pragma unroll
        for (int ti = 0; ti < TBT; ti++){
            ps[ti]  += __shfl_xor(ps[ti],  off);
            pc0[ti] += __shfl_xor(pc0[ti], off);
            pc1[ti] += __shfl_xor(pc1[ti], off);
        }
    }
    if (lane == 0){
        #pragma unroll
        for (int ti = 0; ti < TBT; ti++){
            s_xs[wave][ti]  = ps[ti];
            s_xc0[wave][ti] = pc0[ti];
            s_xc1[wave][ti] = pc1[ti];
        }
    }
    __syncthreads();
    #pragma unroll
    for (int ti = 0; ti < TBT; ti++){
        float S  = s_xs[0][ti] + s_xs[1][ti] + s_xs[2][ti] + s_xs[3][ti];
        float rS = fast_rcp(S);
        s_wsmT[w][ti] = e[ti] * rS;
    }
    if (tid < TBT){
        int ti = tid;
        float S  = s_xs[0][ti] + s_xs[1][ti] + s_xs[2][ti] + s_xs[3][ti];
        float rS = fast_rcp(S);
        s_wc0[ti] = (s_xc0[0][ti] + s_xc0[1][ti] + s_xc0[2][ti] + s_xc0[3][ti]) * rS;
        s_wc1[ti] = (s_xc1[0][ti] + s_xc1[1][ti] + s_xc1[2][ti] + s_xc1[3][ti]) * rS;
    }
    __syncthreads();

    int wid = wave;
    int dq  = lane;
    const float* fbase = feat + (size_t)n*WT*DIM + dq*4;
    float4 acc[TBT];
    #pragma unroll
    for (int i = 0; i < TBT; i++) acc[i] = make_float4(0.f, 0.f, 0.f, 0.f);

    #pragma unroll 4
    for (int w0 = wid; w0 < WT; w0 += 4){
        float4 f = *(const float4*)(fbase + (size_t)w0*DIM);
        const float4* wp = (const float4*)&s_wsmT[w0][0];
        float4 wA = wp[0], wB = wp[1];
        fma4(acc[0], wA.x, f); fma4(acc[1], wA.y, f);
        fma4(acc[2], wA.z, f); fma4(acc[3], wA.w, f);
        fma4(acc[4], wB.x, f); fma4(acc[5], wB.y, f);
        fma4(acc[6], wB.z, f); fma4(acc[7], wB.w, f);
    }

    float pw0 = p1w[tid], pw1 = p1w[DIM + tid], pbv = p1b[tid];
    float* orow = out + ((size_t)n*TT + t0)*DIM;
    #pragma unroll
    for (int ti = 0; ti < TBT; ti++){
        __syncthreads();
        *(float4*)&s_out[wid][dq*4] = acc[ti];
        __syncthreads();
        float r = s_out[0][tid] + s_out[1][tid] + s_out[2][tid] + s_out[3][tid];
        float o = fmaf(s_wc0[ti], pw0, fmaf(s_wc1[ti], pw1, r + pbv));
        orow[(size_t)ti*DIM + tid] = o;
    }
}

extern "C" void kernel_launch(void* const* d_in, const int* in_sizes, int n_in,
                              void* d_out, int out_size, void* d_ws, size_t ws_size,
                              hipStream_t stream)
{
    const float* Tg    = (const float*)d_in[0];
    const float* dur   = (const float*)d_in[1];
    const float* feat  = (const float*)d_in[2];
    const float* c1w   = (const float*)d_in[3];
    const float* c1b   = (const float*)d_in[4];
    const float* bn1g  = (const float*)d_in[5];
    const float* bn1b  = (const float*)d_in[6];
    const float* bn1m  = (const float*)d_in[7];
    const float* bn1v  = (const float*)d_in[8];
    const float* c2w   = (const float*)d_in[9];
    const float* c2b   = (const float*)d_in[10];
    const float* bn2g  = (const float*)d_in[11];
    const float* bn2b  = (const float*)d_in[12];
    const float* bn2m  = (const float*)d_in[13];
    const float* bn2v  = (const float*)d_in[14];
    const float* sb1w1 = (const float*)d_in[15];
    const float* sb1b1 = (const float*)d_in[16];
    const float* sb1w2 = (const float*)d_in[17];
    const float* sb1b2 = (const float*)d_in[18];
    const float* sb2w1 = (const float*)d_in[19];
    const float* sb2b1 = (const float*)d_in[20];
    const float* sb2w2 = (const float*)d_in[21];
    const float* sb2b2 = (const float*)d_in[22];
    const float* p1w   = (const float*)d_in[23];
    const float* p1b   = (const float*)d_in[24];
    const float* p2w   = (const float*)d_in[25];
    const float* p2b   = (const float*)d_in[26];
    float* out = (float*)d_out;

    // ws layout (float units): ts[4096] te[4096] v1[8192] v2[65536]
    // then bf16: featP[NN*WT*DIM]
    float* ws = (float*)d_ws;
    float* ts  = ws;
    float* te  = ws + 4096;
    float* v1  = ws + 8192;
    float* v2  = ws + 16384;
    unsigned short* featP = (unsigned short*)(ws + 16384 + 65536);
    size_t need = ((size_t)16384 + 65536)*sizeof(float)
                + (size_t)NN*WT*DIM*sizeof(unsigned short);

    cumsum_k<<<NN, WT, 0, stream>>>(dur, ts, te);
    prep_k<<<dim3(WT, NN), 256, 0, stream>>>(feat, c1w, c1b, bn1g, bn1b, bn1m, bn1v,
                                             c2w, c2b, bn2g, bn2b, bn2m, bn2v,
                                             sb1w1, sb1b1, sb2w1, sb2b1, ts, te, v1, v2);
    if (ws_size >= need){
        featpack_k<<<dim3(8, NN), 256, 0, stream>>>(feat, featP);
        scoreout_k<<<dim3(TT/TBS, NN), 256, 0, stream>>>(Tg, v1, v2,
                                                         sb1w1, sb1w2, sb1b2,
                                                         sb2w1, sb2w2, sb2b2,
                                                         p2w, p2b, featP, p1w, p1b, out);
    } else {
        fused_k<<<dim3(TT/TBT, NN), 256, 0, stream>>>(Tg, feat, v1, v2,
                                                      sb1w1, sb1w2, sb1b2,
                                                      sb2w1, sb2w2, sb2b2,
                                                      p1w, p1b, p2w, p2b, out);
    }
}

// Round 10
// 288.669 us; speedup vs baseline: 1.3029x; 1.3029x over previous
//
#include <hip/hip_runtime.h>
#include <hip/hip_bf16.h>

#define NN  16
#define WT  256
#define TT  2048
#define DIM 256
#define TBT 8      // t-values per block in score kernel

typedef __attribute__((ext_vector_type(8))) short short8_t;  // 8 bf16 (4 VGPRs)
typedef __attribute__((ext_vector_type(4))) float f32x4;     // MFMA acc

__device__ __forceinline__ float fast_rcp(float x){ return __builtin_amdgcn_rcpf(x); }

__device__ __forceinline__ float silu_f(float x){
    return x * fast_rcp(1.0f + __expf(-x));
}

__device__ __forceinline__ unsigned short f2bf(float x){
    union { float f; unsigned u; } v; v.f = x;
    unsigned r = v.u + 0x7FFFu + ((v.u >> 16) & 1u);   // round-to-nearest-even
    return (unsigned short)(r >> 16);
}

__device__ __forceinline__ void fma4(float4& a, float s, const float4& f){
    a.x = fmaf(s, f.x, a.x); a.y = fmaf(s, f.y, a.y);
    a.z = fmaf(s, f.z, a.z); a.w = fmaf(s, f.w, a.w);
}

// ------- Kernel B: cumsum (in-block scan) + conv(3,256->8)+BN+SiLU, fold into v1/v2 -------
// cumsum_k is folded in: each block re-scans its n's 256 durations in LDS
// (redundant across the 256 w-blocks but ~free; removes a launch + ts/te round-trip).
__global__ __launch_bounds__(256) void prep_k(
    const float* __restrict__ dur, const float* __restrict__ feat,
    const float* __restrict__ c1w, const float* __restrict__ c1b,
    const float* __restrict__ g1,  const float* __restrict__ be1,
    const float* __restrict__ m1,  const float* __restrict__ vv1,
    const float* __restrict__ c2w, const float* __restrict__ c2b,
    const float* __restrict__ g2,  const float* __restrict__ be2,
    const float* __restrict__ m2,  const float* __restrict__ vv2,
    const float* __restrict__ sb1w1, const float* __restrict__ sb1b1,
    const float* __restrict__ sb2w1, const float* __restrict__ sb2b1,
    float* __restrict__ v1o, float* __restrict__ v2o)
{
    int w = blockIdx.x, n = blockIdx.y;
    int tid = threadIdx.x;              // channel c

    // ---- in-block inclusive scan of durations for this n ----
    __shared__ float sdur[WT];
    sdur[tid] = dur[n*WT + tid];
    __syncthreads();
    for (int off = 1; off < WT; off <<= 1){
        float v = (tid >= off) ? sdur[tid-off] : 0.0f;
        __syncthreads();
        sdur[tid] += v;
        __syncthreads();
    }
    float end   = sdur[w];              // broadcast read
    float start = end - dur[n*WT + w];  // uniform scalar load

    const float* fb = feat + (size_t)(n*WT)*DIM;
    float fm = (w > 0)    ? fb[(size_t)(w-1)*DIM + tid] : 0.0f;
    float f0 =              fb[(size_t) w   *DIM + tid];
    float fp = (w < WT-1) ? fb[(size_t)(w+1)*DIM + tid] : 0.0f;

    float pl[8], pr[8];
    #pragma unroll
    for (int o = 0; o < 8; o++){
        const float* wp = c1w + (size_t)(o*DIM + tid)*3;
        pl[o] = fmaf(fm, wp[0], fmaf(f0, wp[1], fp*wp[2]));
        const float* wq = c2w + (size_t)(o*DIM + tid)*3;
        pr[o] = fmaf(fm, wq[0], fmaf(f0, wq[1], fp*wq[2]));
    }
    #pragma unroll
    for (int o = 0; o < 8; o++){
        #pragma unroll
        for (int off = 32; off; off >>= 1){
            pl[o] += __shfl_xor(pl[o], off);
            pr[o] += __shfl_xor(pr[o], off);
        }
    }
    __shared__ float sws[4][16];
    int wave = tid >> 6, lane = tid & 63;
    if (lane == 0){
        #pragma unroll
        for (int o = 0; o < 8; o++){ sws[wave][o] = pl[o]; sws[wave][8+o] = pr[o]; }
    }
    __syncthreads();
    __shared__ float slr[16];   // [0..7]=left(SiLU'd), [8..15]=right
    if (tid < 16){
        float s = sws[0][tid] + sws[1][tid] + sws[2][tid] + sws[3][tid];
        int o = tid & 7; bool isr = tid >= 8;
        float bias = isr ? c2b[o] : c1b[o];
        float mm   = isr ? m2[o]  : m1[o];
        float vv   = isr ? vv2[o] : vv1[o];
        float gg   = isr ? g2[o]  : g1[o];
        float bb   = isr ? be2[o] : be1[o];
        float y = s + bias;
        y = (y - mm) * rsqrtf(vv + 1e-5f);
        y = y * gg + bb;
        slr[tid] = silu_f(y);
    }
    __syncthreads();
    if (tid < 16){
        int j = tid;
        float acc = sb2b1[j] - start*sb2w1[j] + end*sb2w1[16 + j];
        #pragma unroll
        for (int o = 0; o < 8; o++) acc = fmaf(slr[8+o], sb2w1[(2+o)*16 + j], acc);
        v2o[(size_t)(n*WT + w)*16 + j] = acc;
    } else if (tid < 18){
        int p = tid - 16;
        float acc = sb1b1[p] - start*sb1w1[p] + end*sb1w1[2 + p];
        #pragma unroll
        for (int o = 0; o < 8; o++) acc = fmaf(slr[o], sb1w1[(2+o)*2 + p], acc);
        v1o[(size_t)(n*WT + w)*2 + p] = acc;
    }
}

// ------- Kernel B2: pack feat into B-fragment bf16 layout [n][w/32][d][w%32] -------
__global__ __launch_bounds__(256) void featpack_k(const float* __restrict__ feat,
                                                  unsigned short* __restrict__ featP)
{
    int kb = blockIdx.x, n = blockIdx.y;   // kb = 0..7 (k-block of 32 w's)
    int d = threadIdx.x;
    const float* fb = feat + (size_t)n*WT*DIM + (size_t)kb*32*DIM + d;
    unsigned short* op = featP + ((size_t)(n*8 + kb)*DIM + d)*32;
    unsigned short buf[32];
    #pragma unroll
    for (int e = 0; e < 32; e++) buf[e] = f2bf(fb[(size_t)e*DIM]);   // coalesced reads
    #pragma unroll
    for (int g = 0; g < 4; g++){
        uint4 u;
        u.x = (unsigned)buf[g*8+0] | ((unsigned)buf[g*8+1] << 16);
        u.y = (unsigned)buf[g*8+2] | ((unsigned)buf[g*8+3] << 16);
        u.z = (unsigned)buf[g*8+4] | ((unsigned)buf[g*8+5] << 16);
        u.w = (unsigned)buf[g*8+6] | ((unsigned)buf[g*8+7] << 16);
        *(uint4*)(op + g*8) = u;
    }
}

// ---------------- Kernel C1: scores -> softmax weights (bf16, to global ws) ----------------
// EXACT R5 form: LDS-staged weights, scalar matvec, ti in pairs.
// Measured 139.5 us @ 84 VGPR / 94% VALUBusy — every perturbation
// (f32x2 pack, b128 LDS loads, SGPR weights, fusion) regressed. Do not touch.
__global__ __launch_bounds__(256) void score_k(
    const float* __restrict__ Tg,
    const float* __restrict__ v1g, const float* __restrict__ v2g,
    const float* __restrict__ sb1w1, const float* __restrict__ sb1w2, const float* __restrict__ sb1b2,
    const float* __restrict__ sb2w1, const float* __restrict__ sb2w2, const float* __restrict__ sb2b2,
    const float* __restrict__ p2w, const float* __restrict__ p2b,
    unsigned short* __restrict__ wsm_b, float* __restrict__ wc_g)
{
    int n   = blockIdx.y;
    int t0  = blockIdx.x * TBT;
    int tid = threadIdx.x;
    int w   = tid;
    int lane = tid & 63, wave = tid >> 6;

    __shared__ float s_w2[16*16];
    __shared__ float s_u2[16], s_b2[16], s_p2w[16];
    __shared__ float s_u1[2], s_w21[4], s_b21[2];
    __shared__ float s_xa[4][TBT];
    __shared__ float s_xs[4][TBT];
    __shared__ float s_xc0[4][TBT], s_xc1[4][TBT];

    s_w2[tid] = sb2w2[tid];
    if (tid < 16){
        s_u2[tid]  = sb2w1[tid] - sb2w1[16 + tid];
        s_b2[tid]  = sb2b2[tid];
        s_p2w[tid] = p2w[tid];
    } else if (tid < 18){
        int p = tid - 16;
        s_u1[p]  = sb1w1[p] - sb1w1[2 + p];
        s_b21[p] = sb1b2[p];
    } else if (tid < 22){
        s_w21[tid - 18] = sb1w2[tid - 18];
    }
    __syncthreads();

    float v2r[16];
    {
        const float4* vp = (const float4*)(v2g + (size_t)(n*WT + w)*16);
        float4 a = vp[0], b = vp[1], c = vp[2], d = vp[3];
        v2r[0]=a.x; v2r[1]=a.y; v2r[2]=a.z; v2r[3]=a.w;
        v2r[4]=b.x; v2r[5]=b.y; v2r[6]=b.z; v2r[7]=b.w;
        v2r[8]=c.x; v2r[9]=c.y; v2r[10]=c.z; v2r[11]=c.w;
        v2r[12]=d.x; v2r[13]=d.y; v2r[14]=d.z; v2r[15]=d.w;
    }
    float v1r0, v1r1;
    {
        const float* vp = v1g + (size_t)(n*WT + w)*2;
        v1r0 = vp[0]; v1r1 = vp[1];
    }
    float p2bv = p2b[0];
    float tv[TBT];
    #pragma unroll
    for (int ti = 0; ti < TBT; ti++) tv[ti] = Tg[t0 + ti];

    float scores[TBT];
    #pragma unroll
    for (int tp = 0; tp < TBT; tp += 2){
        float h2a[16], h2b[16];
        #pragma unroll
        for (int j = 0; j < 16; j++){ float b = s_b2[j]; h2a[j] = b; h2b[j] = b; }
        #pragma unroll
        for (int i = 0; i < 16; i++){
            float u = s_u2[i], v = v2r[i];
            float aa = silu_f(fmaf(tv[tp],   u, v));
            float ab = silu_f(fmaf(tv[tp+1], u, v));
            #pragma unroll
            for (int j = 0; j < 16; j++){
                float wv = s_w2[i*16 + j];
                h2a[j] = fmaf(aa, wv, h2a[j]);
                h2b[j] = fmaf(ab, wv, h2b[j]);
            }
        }
        float sa = p2bv, sb = p2bv;
        #pragma unroll
        for (int j = 0; j < 16; j++){
            float pw = s_p2w[j];
            sa = fmaf(silu_f(h2a[j]), pw, sa);
            sb = fmaf(silu_f(h2b[j]), pw, sb);
        }
        scores[tp] = sa; scores[tp+1] = sb;
    }

    float c0r[TBT], c1r[TBT];
    {
        float u10 = s_u1[0], u11 = s_u1[1];
        float w00 = s_w21[0], w01 = s_w21[1], w10 = s_w21[2], w11 = s_w21[3];
        float b0 = s_b21[0], b1 = s_b21[1];
        #pragma unroll
        for (int ti = 0; ti < TBT; ti++){
            float gl0 = silu_f(fmaf(tv[ti], u10, v1r0));
            float gl1 = silu_f(fmaf(tv[ti], u11, v1r1));
            c0r[ti] = silu_f(fmaf(gl0, w00, fmaf(gl1, w10, b0)));
            c1r[ti] = silu_f(fmaf(gl0, w01, fmaf(gl1, w11, b1)));
        }
    }

    float m[TBT];
    #pragma unroll
    for (int ti = 0; ti < TBT; ti++) m[ti] = scores[ti];
    #pragma unroll
    for (int off = 32; off; off >>= 1){
        #pragma unroll
        for (int ti = 0; ti < TBT; ti++) m[ti] = fmaxf(m[ti], __shfl_xor(m[ti], off));
    }
    if (lane == 0){
        #pragma unroll
        for (int ti = 0; ti < TBT; ti++) s_xa[wave][ti] = m[ti];
    }
    __syncthreads();
    #pragma unroll
    for (int ti = 0; ti < TBT; ti++)
        m[ti] = fmaxf(fmaxf(s_xa[0][ti], s_xa[1][ti]), fmaxf(s_xa[2][ti], s_xa[3][ti]));

    float e[TBT], ps[TBT], pc0[TBT], pc1[TBT];
    #pragma unroll
    for (int ti = 0; ti < TBT; ti++){
        e[ti]   = __expf(scores[ti] - m[ti]);
        ps[ti]  = e[ti];
        pc0[ti] = e[ti] * c0r[ti];
        pc1[ti] = e[ti] * c1r[ti];
    }
    #pragma unroll
    for (int off = 32; off; off >>= 1){
        #pragma unroll
        for (int ti = 0; ti < TBT; ti++){
            ps[ti]  += __shfl_xor(ps[ti],  off);
            pc0[ti] += __shfl_xor(pc0[ti], off);
            pc1[ti] += __shfl_xor(pc1[ti], off);
        }
    }
    if (lane == 0){
        #pragma unroll
        for (int ti = 0; ti < TBT; ti++){
            s_xs[wave][ti]  = ps[ti];
            s_xc0[wave][ti] = pc0[ti];
            s_xc1[wave][ti] = pc1[ti];
        }
    }
    __syncthreads();

    unsigned short* wbase = wsm_b + ((size_t)n*TT + t0)*WT + w;
    #pragma unroll
    for (int ti = 0; ti < TBT; ti++){
        float S  = s_xs[0][ti] + s_xs[1][ti] + s_xs[2][ti] + s_xs[3][ti];
        float rS = fast_rcp(S);
        wbase[(size_t)ti*WT] = f2bf(e[ti] * rS);
    }
    if (tid < TBT){
        int ti = tid;
        float S  = s_xs[0][ti] + s_xs[1][ti] + s_xs[2][ti] + s_xs[3][ti];
        float rS = fast_rcp(S);
        float2 wc;
        wc.x = (s_xc0[0][ti] + s_xc0[1][ti] + s_xc0[2][ti] + s_xc0[3][ti]) * rS;
        wc.y = (s_xc1[0][ti] + s_xc1[1][ti] + s_xc1[2][ti] + s_xc1[3][ti]) * rS;
        *(float2*)(wc_g + ((size_t)n*TT + t0 + ti)*2) = wc;
    }
}

// ---------------- Kernel C2: out_r via bf16 MFMA GEMM + epilogue (R7 form) ----------------
// Block = 512 threads = 8 waves, covers 32t x 256d.  Wave = 16t x 64d strip
// (acc 4 x f32x4 = 16 VGPR): 8192 waves -> full latency hiding.  Zero LDS.
__global__ __launch_bounds__(512) void outr_mfma_k(
    const unsigned short* __restrict__ wsmB, const unsigned short* __restrict__ featP,
    const float* __restrict__ wc_g,
    const float* __restrict__ p1w, const float* __restrict__ p1b,
    float* __restrict__ out)
{
    int n    = blockIdx.y;
    int t0   = blockIdx.x * 32;
    int tid  = threadIdx.x;
    int lane = tid & 63, wave = tid >> 6;
    int tw   = t0 + (wave >> 2) * 16;    // waves 0-3 -> t0, 4-7 -> t0+16
    int dbase = (wave & 3) * 4;          // 4 dt-blocks (64 d) per wave
    int l15  = lane & 15, quad = lane >> 4;

    f32x4 acc[4];
    #pragma unroll
    for (int dt = 0; dt < 4; dt++) acc[dt] = (f32x4){0.f, 0.f, 0.f, 0.f};

    const unsigned short* aPtr = wsmB + ((size_t)(n*TT + tw + l15))*WT + quad*8;

    #pragma unroll
    for (int kb = 0; kb < 8; kb++){
        short8_t af = *(const short8_t*)(aPtr + kb*32);
        const unsigned short* bp = featP + ((size_t)(n*8 + kb)*DIM + dbase*16 + l15)*32 + quad*8;
        #pragma unroll
        for (int dt = 0; dt < 4; dt++){
            short8_t bf = *(const short8_t*)(bp + (size_t)dt*16*32);
            acc[dt] = __builtin_amdgcn_mfma_f32_16x16x32_bf16(af, bf, acc[dt], 0, 0, 0);
        }
    }

    float wc0[4], wc1[4];
    #pragma unroll
    for (int r = 0; r < 4; r++){
        const float* wp = wc_g + ((size_t)(n*TT + tw + quad*4 + r))*2;
        wc0[r] = wp[0]; wc1[r] = wp[1];
    }
    float* obase = out + ((size_t)(n*TT + tw + quad*4))*DIM;
    #pragma unroll
    for (int dt = 0; dt < 4; dt++){
        int d = (dbase + dt)*16 + l15;   // D col
        float pa = p1w[d], pb2 = p1w[DIM + d], pc = p1b[d];
        #pragma unroll
        for (int r = 0; r < 4; r++){     // D row = quad*4 + r
            float val = acc[dt][r] + fmaf(wc0[r], pa, fmaf(wc1[r], pb2, pc));
            obase[(size_t)r*DIM + d] = val;
        }
    }
}

// ---------------- Fallback fused kernel (R1, known-good) if ws too small ----------------
__global__ __launch_bounds__(256) void fused_k(
    const float* __restrict__ Tg, const float* __restrict__ feat,
    const float* __restrict__ v1g, const float* __restrict__ v2g,
    const float* __restrict__ sb1w1, const float* __restrict__ sb1w2, const float* __restrict__ sb1b2,
    const float* __restrict__ sb2w1, const float* __restrict__ sb2w2, const float* __restrict__ sb2b2,
    const float* __restrict__ p1w, const float* __restrict__ p1b,
    const float* __restrict__ p2w, const float* __restrict__ p2b,
    float* __restrict__ out)
{
    int n   = blockIdx.y;
    int t0  = blockIdx.x * TBT;
    int tid = threadIdx.x;
    int w   = tid;
    int lane = tid & 63, wave = tid >> 6;

    __shared__ float s_w2[16*16];
    __shared__ float s_u2[16], s_b2[16], s_p2w[16];
    __shared__ float s_u1[2], s_w21[4], s_b21[2];
    __shared__ float s_wsmT[WT][TBT];
    __shared__ float s_xa[4][TBT];
    __shared__ float s_xs[4][TBT];
    __shared__ float s_xc0[4][TBT], s_xc1[4][TBT];
    __shared__ float s_wc0[TBT], s_wc1[TBT];
    __shared__ float s_out[4][DIM];

    s_w2[tid] = sb2w2[tid];
    if (tid < 16){
        s_u2[tid]  = sb2w1[tid] - sb2w1[16 + tid];
        s_b2[tid]  = sb2b2[tid];
        s_p2w[tid] = p2w[tid];
    } else if (tid < 18){
        int p = tid - 16;
        s_u1[p]  = sb1w1[p] - sb1w1[2 + p];
        s_b21[p] = sb1b2[p];
    } else if (tid < 22){
        s_w21[tid - 18] = sb1w2[tid - 18];
    }
    __syncthreads();

    float v2r[16];
    {
        const float4* vp = (const float4*)(v2g + (size_t)(n*WT + w)*16);
        float4 a = vp[0], b = vp[1], c = vp[2], d = vp[3];
        v2r[0]=a.x; v2r[1]=a.y; v2r[2]=a.z; v2r[3]=a.w;
        v2r[4]=b.x; v2r[5]=b.y; v2r[6]=b.z; v2r[7]=b.w;
        v2r[8]=c.x; v2r[9]=c.y; v2r[10]=c.z; v2r[11]=c.w;
        v2r[12]=d.x; v2r[13]=d.y; v2r[14]=d.z; v2r[15]=d.w;
    }
    float v1r0, v1r1;
    {
        const float* vp = v1g + (size_t)(n*WT + w)*2;
        v1r0 = vp[0]; v1r1 = vp[1];
    }
    float p2bv = p2b[0];
    float tv[TBT];
    #pragma unroll
    for (int ti = 0; ti < TBT; ti++) tv[ti] = Tg[t0 + ti];

    float scores[TBT];
    #pragma unroll
    for (int tp = 0; tp < TBT; tp += 2){
        float h2a[16], h2b[16];
        #pragma unroll
        for (int j = 0; j < 16; j++){ float b = s_b2[j]; h2a[j] = b; h2b[j] = b; }
        #pragma unroll
        for (int i = 0; i < 16; i++){
            float u = s_u2[i], v = v2r[i];
            float aa = silu_f(fmaf(tv[tp],   u, v));
            float ab = silu_f(fmaf(tv[tp+1], u, v));
            #pragma unroll
            for (int j = 0; j < 16; j++){
                float wv = s_w2[i*16 + j];
                h2a[j] = fmaf(aa, wv, h2a[j]);
                h2b[j] = fmaf(ab, wv, h2b[j]);
            }
        }
        float sa = p2bv, sb = p2bv;
        #pragma unroll
        for (int j = 0; j < 16; j++){
            float pw = s_p2w[j];
            sa = fmaf(silu_f(h2a[j]), pw, sa);
            sb = fmaf(silu_f(h2b[j]), pw, sb);
        }
        scores[tp] = sa; scores[tp+1] = sb;
    }

    float c0r[TBT], c1r[TBT];
    {
        float u10 = s_u1[0], u11 = s_u1[1];
        float w00 = s_w21[0], w01 = s_w21[1], w10 = s_w21[2], w11 = s_w21[3];
        float b0 = s_b21[0], b1 = s_b21[1];
        #pragma unroll
        for (int ti = 0; ti < TBT; ti++){
            float gl0 = silu_f(fmaf(tv[ti], u10, v1r0));
            float gl1 = silu_f(fmaf(tv[ti], u11, v1r1));
            c0r[ti] = silu_f(fmaf(gl0, w00, fmaf(gl1, w10, b0)));
            c1r[ti] = silu_f(fmaf(gl0, w01, fmaf(gl1, w11, b1)));
        }
    }

    float m[TBT];
    #pragma unroll
    for (int ti = 0; ti < TBT; ti++) m[ti] = scores[ti];
    #pragma unroll
    for (int off = 32; off; off >>= 1){
        #pragma unroll
        for (int ti = 0; ti < TBT; ti++) m[ti] = fmaxf(m[ti], __shfl_xor(m[ti], off));
    }
    if (lane == 0){
        #pragma unroll
        for (int ti = 0; ti < TBT; ti++) s_xa[wave][ti] = m[ti];
    }
    __syncthreads();
    #pragma unroll
    for (int ti = 0; ti < TBT; ti++)
        m[ti] = fmaxf(fmaxf(s_xa[0][ti], s_xa[1][ti]), fmaxf(s_xa[2][ti], s_xa[3][ti]));

    float e[TBT], ps[TBT], pc0[TBT], pc1[TBT];
    #pragma unroll
    for (int ti = 0; ti < TBT; ti++){
        e[ti]  = __expf(scores[ti] - m[ti]);
        ps[ti] = e[ti];
        pc0[ti] = e[ti] * c0r[ti];
        pc1[ti] = e[ti] * c1r[ti];
    }
    #pragma unroll
    for (int off = 32; off; off >>= 1){
        #pragma unroll
        for (int ti = 0; ti < TBT; ti++){
            ps[ti]  += __shfl_xor(ps[ti],  off);
            pc0[ti] += __shfl_xor(pc0[ti], off);
            pc1[ti] += __shfl_xor(pc1[ti], off);
        }
    }
    if (lane == 0){
        #pragma unroll
        for (int ti = 0; ti < TBT; ti++){
            s_xs[wave][ti]  = ps[ti];
            s_xc0[wave][ti] = pc0[ti];
            s_xc1[wave][ti] = pc1[ti];
        }
    }
    __syncthreads();
    #pragma unroll
    for (int ti = 0; ti < TBT; ti++){
        float S  = s_xs[0][ti] + s_xs[1][ti] + s_xs[2][ti] + s_xs[3][ti];
        float rS = fast_rcp(S);
        s_wsmT[w][ti] = e[ti] * rS;
    }
    if (tid < TBT){
        int ti = tid;
        float S  = s_xs[0][ti] + s_xs[1][ti] + s_xs[2][ti] + s_xs[3][ti];
        float rS = fast_rcp(S);
        s_wc0[ti] = (s_xc0[0][ti] + s_xc0[1][ti] + s_xc0[2][ti] + s_xc0[3][ti]) * rS;
        s_wc1[ti] = (s_xc1[0][ti] + s_xc1[1][ti] + s_xc1[2][ti] + s_xc1[3][ti]) * rS;
    }
    __syncthreads();

    int wid = wave;
    int dq  = lane;
    const float* fbase = feat + (size_t)n*WT*DIM + dq*4;
    float4 acc[TBT];
    #pragma unroll
    for (int i = 0; i < TBT; i++) acc[i] = make_float4(0.f, 0.f, 0.f, 0.f);

    #pragma unroll 4
    for (int w0 = wid; w0 < WT; w0 += 4){
        float4 f = *(const float4*)(fbase + (size_t)w0*DIM);
        const float4* wp = (const float4*)&s_wsmT[w0][0];
        float4 wA = wp[0], wB = wp[1];
        fma4(acc[0], wA.x, f); fma4(acc[1], wA.y, f);
        fma4(acc[2], wA.z, f); fma4(acc[3], wA.w, f);
        fma4(acc[4], wB.x, f); fma4(acc[5], wB.y, f);
        fma4(acc[6], wB.z, f); fma4(acc[7], wB.w, f);
    }

    float pw0 = p1w[tid], pw1 = p1w[DIM + tid], pbv = p1b[tid];
    float* orow = out + ((size_t)n*TT + t0)*DIM;
    #pragma unroll
    for (int ti = 0; ti < TBT; ti++){
        __syncthreads();
        *(float4*)&s_out[wid][dq*4] = acc[ti];
        __syncthreads();
        float r = s_out[0][tid] + s_out[1][tid] + s_out[2][tid] + s_out[3][tid];
        float o = fmaf(s_wc0[ti], pw0, fmaf(s_wc1[ti], pw1, r + pbv));
        orow[(size_t)ti*DIM + tid] = o;
    }
}

extern "C" void kernel_launch(void* const* d_in, const int* in_sizes, int n_in,
                              void* d_out, int out_size, void* d_ws, size_t ws_size,
                              hipStream_t stream)
{
    const float* Tg    = (const float*)d_in[0];
    const float* dur   = (const float*)d_in[1];
    const float* feat  = (const float*)d_in[2];
    const float* c1w   = (const float*)d_in[3];
    const float* c1b   = (const float*)d_in[4];
    const float* bn1g  = (const float*)d_in[5];
    const float* bn1b  = (const float*)d_in[6];
    const float* bn1m  = (const float*)d_in[7];
    const float* bn1v  = (const float*)d_in[8];
    const float* c2w   = (const float*)d_in[9];
    const float* c2b   = (const float*)d_in[10];
    const float* bn2g  = (const float*)d_in[11];
    const float* bn2b  = (const float*)d_in[12];
    const float* bn2m  = (const float*)d_in[13];
    const float* bn2v  = (const float*)d_in[14];
    const float* sb1w1 = (const float*)d_in[15];
    const float* sb1b1 = (const float*)d_in[16];
    const float* sb1w2 = (const float*)d_in[17];
    const float* sb1b2 = (const float*)d_in[18];
    const float* sb2w1 = (const float*)d_in[19];
    const float* sb2b1 = (const float*)d_in[20];
    const float* sb2w2 = (const float*)d_in[21];
    const float* sb2b2 = (const float*)d_in[22];
    const float* p1w   = (const float*)d_in[23];
    const float* p1b   = (const float*)d_in[24];
    const float* p2w   = (const float*)d_in[25];
    const float* p2b   = (const float*)d_in[26];
    float* out = (float*)d_out;

    // ws layout (float units): v1[8192] v2[65536] wc[65536]
    // then bf16 arrays: wsmB[NN*TT*WT] featP[NN*WT*DIM]
    float* ws = (float*)d_ws;
    float* v1  = ws;
    float* v2  = ws + 8192;
    float* wc  = ws + 8192 + 65536;
    unsigned short* wsmB  = (unsigned short*)(ws + 8192 + 65536 + 65536);
    unsigned short* featP = wsmB + (size_t)NN*TT*WT;
    size_t need = ((size_t)8192 + 65536 + 65536)*sizeof(float)
                + ((size_t)NN*TT*WT + (size_t)NN*WT*DIM)*sizeof(unsigned short);

    prep_k<<<dim3(WT, NN), 256, 0, stream>>>(dur, feat, c1w, c1b, bn1g, bn1b, bn1m, bn1v,
                                             c2w, c2b, bn2g, bn2b, bn2m, bn2v,
                                             sb1w1, sb1b1, sb2w1, sb2b1, v1, v2);
    if (ws_size >= need){
        featpack_k<<<dim3(8, NN), 256, 0, stream>>>(feat, featP);
        score_k<<<dim3(TT/TBT, NN), 256, 0, stream>>>(Tg, v1, v2,
                                                      sb1w1, sb1w2, sb1b2,
                                                      sb2w1, sb2w2, sb2b2,
                                                      p2w, p2b, wsmB, wc);
        outr_mfma_k<<<dim3(TT/32, NN), 512, 0, stream>>>(wsmB, featP, wc, p1w, p1b, out);
    } else {
        fused_k<<<dim3(TT/TBT, NN), 256, 0, stream>>>(Tg, feat, v1, v2,
                                                      sb1w1, sb1w2, sb1b2,
                                                      sb2w1, sb2w2, sb2b2,
                                                      p1w, p1b, p2w, p2b, out);
    }
}